// Round 1
// baseline (993.661 us; speedup 1.0000x reference)
//
#include <hip/hip_runtime.h>
#include <math.h>

// Problem constants
#define BB   4
#define SS   96
#define NN   512
#define DD   8
#define HH   64
#define G4   256    // 4*H
#define OUTK 24

#define THREADS 512
#define NBLK    256   // 4 batches x 64 blocks, cooperative (co-resident, 1/CU)
#define RPB     8     // adj rows per block
#define AST     580   // a_lds row stride
#define AHWS    516   // u_lds per-wave stride
#define ITEM    64    // u32 per barrier slot (256 B)
#define BSTR    (10 * ITEM)   // per-batch barrier stride: 8 leaf + root + (spare)

typedef float f32x4 __attribute__((ext_vector_type(4)));

// ---------------------------------------------------------------------------
__global__ void bar_init(unsigned* __restrict__ bar) {
    const int i = blockIdx.x * 256 + threadIdx.x;
    if (i < BB * BSTR) bar[i] = 0u;
}

__device__ __forceinline__ float sigm_f(float v) { return 1.f / (1.f + __expf(-v)); }
__device__ __forceinline__ float tanh_f(float v) { return 1.f - 2.f / (__expf(2.f * v) + 1.f); }

__device__ __forceinline__ void vfma(f32x4& d, float s, f32x4 v) {
    d.x = fmaf(s, v.x, d.x); d.y = fmaf(s, v.y, d.y);
    d.z = fmaf(s, v.z, d.z); d.w = fmaf(s, v.w, d.w);
}

// ---------------------------------------------------------------------------
__global__ __launch_bounds__(THREADS, 2) void gnn_lstm_persist(
    const float* __restrict__ x,    // [B][S][N][D]
    const float* __restrict__ adj,  // [B][S][N][N]
    const float* __restrict__ h0,   // [B][N][H]
    const float* __restrict__ c0,   // [B][N][H]
    const float* __restrict__ Wx,   // [D][256]
    const float* __restrict__ Wh,   // [H][256]
    const float* __restrict__ bg,   // [256]
    const float* __restrict__ W1, const float* __restrict__ b1,
    const float* __restrict__ W2, const float* __restrict__ b2,
    float* __restrict__ out,        // [4][24]
    float* __restrict__ hA, float* __restrict__ hB,
    unsigned* __restrict__ bar)
{
    __shared__ float a_lds[RPB * AST];   // adj tile (stride-swizzled)
    __shared__ float x_lds[NN * DD];     // x slice
    __shared__ float u_lds[8 * AHWS];    // union: ah wave-partials | g partials
    __shared__ float ax_part[THREADS];
    __shared__ float ah_lds[RPB * HH];
    __shared__ float ax_s[RPB * DD];
    __shared__ float hh_s[HH];
    __shared__ float z1_s[32];

    const int tid  = threadIdx.x;
    const int bid  = blockIdx.x;
    const int b    = bid >> 6;           // batch
    const int slot = bid & 63;           // 0..63 within batch
    const int n0   = slot * RPB;
    const int r_g  = tid >> 6;           // wave id = owned row
    const int j_g  = tid & 63;

    // per-batch tree barrier (all atomics RELAXED; no fences anywhere)
    unsigned* const bgrp  = bar + b * BSTR + (bid & 7) * ITEM;  // leaf: 8 members
    unsigned* const broot = bar + b * BSTR + 8 * ITEM;

    // ---- persistent per-thread state -------------------------------------
    const int half = tid >> 8;           // 0/1
    const int jj   = tid & 255;          // gate column
    float whcol[36];
    if (half == 0) {
        #pragma unroll
        for (int k = 0; k < 36; ++k) whcol[k] = Wh[k * G4 + jj];
    } else {
        #pragma unroll
        for (int k = 0; k < 28; ++k) whcol[k] = Wh[(36 + k) * G4 + jj];
        #pragma unroll
        for (int d = 0; d < 8; ++d)  whcol[28 + d] = Wx[d * G4 + jj];
    }
    const float bias = (half == 0) ? bg[jj] : 0.f;
    const size_t sidx = ((size_t)b * NN + n0 + r_g) * HH + j_g;
    float c_reg = c0[sidx];

    // ---- stage adj(0), x(0) ----------------------------------------------
    {
        const float* ab = adj + (((size_t)b * SS + 0) * NN + n0) * NN;
        const float* xb = x + ((size_t)b * SS + 0) * (NN * DD);
        float4 pa0 = *(const float4*)(ab + tid * 4);
        float4 pa1 = *(const float4*)(ab + 2048 + tid * 4);
        float4 px0 = *(const float4*)(xb + tid * 4);
        float4 px1 = *(const float4*)(xb + 2048 + tid * 4);
        const int f0 = tid * 4;
        *(float4*)(a_lds + (f0 >> 9) * AST + (f0 & 511)) = pa0;
        const int f1 = 2048 + tid * 4;
        *(float4*)(a_lds + (f1 >> 9) * AST + (f1 & 511)) = pa1;
        *(float4*)(x_lds + tid * 4) = px0;
        *(float4*)(x_lds + 2048 + tid * 4) = px1;
    }
    __syncthreads();

    // ---- reg prefetch t=1 ----
    float4 qa0, qa1, qx0, qx1;
    {
        const float* ab = adj + (((size_t)b * SS + 1) * NN + n0) * NN;
        const float* xb = x + ((size_t)b * SS + 1) * (NN * DD);
        qa0 = *(const float4*)(ab + tid * 4);
        qa1 = *(const float4*)(ab + 2048 + tid * 4);
        qx0 = *(const float4*)(xb + tid * 4);
        qx1 = *(const float4*)(xb + 2048 + tid * 4);
    }

    // ---- x-agg partials for t=0 ----
    {
        const int d = tid & 7, rr = (tid >> 3) & 7, mg2 = tid >> 6;
        const float* ar = a_lds + rr * AST + mg2 * 64;
        const float* xr = x_lds + mg2 * 512 + d;
        float s = 0.f;
        #pragma unroll
        for (int mi = 0; mi < 64; ++mi) s = fmaf(ar[mi], xr[mi * 8], s);
        ax_part[tid] = s;
    }

    const float* hp = h0;
    float* hd = hB;

    const int c4 = (tid & 15) * 4;
    const int m0 = (tid >> 4) * 16;

    // ---- main recurrence -------------------------------------------------
    for (int t = 0; t < SS; ++t) {
        // phase A: 16 h-row loads. L1-bypass only (sc0); per-XCD L2 was
        // flash-invalidated (buffer_inv sc1) after the previous step's poll,
        // so L2 serves fresh IC data and each line is IC-fetched once per XCD.
        f32x4 hv[16];
        {
            const float* hpb = hp + (size_t)b * NN * HH;
            const unsigned long long hbase =
                (unsigned long long)(const void*)(hpb + (size_t)m0 * HH + c4);
#define HLOAD(I, OFFS) \
            asm volatile("global_load_dwordx4 %0, %1, off offset:" OFFS " sc0" \
                         : "=v"(hv[I]) : "v"(hbase) : "memory")
            HLOAD(0, "0");     HLOAD(1, "256");   HLOAD(2, "512");   HLOAD(3, "768");
            HLOAD(4, "1024");  HLOAD(5, "1280");  HLOAD(6, "1536");  HLOAD(7, "1792");
            HLOAD(8, "2048");  HLOAD(9, "2304");  HLOAD(10, "2560"); HLOAD(11, "2816");
            HLOAD(12, "3072"); HLOAD(13, "3328"); HLOAD(14, "3584"); HLOAD(15, "3840");
#undef HLOAD
        }
        // per-thread 8-row x 4-col tile, pipelined against the load burst:
        // staged vmcnt waits let FMA chunk i overlap the in-flight tail.
        {
            f32x4 acc[8];
            #pragma unroll
            for (int r = 0; r < 8; ++r) acc[r] = f32x4{0.f, 0.f, 0.f, 0.f};
#define AH_CHUNK(MI4) \
            { \
                _Pragma("unroll") \
                for (int r = 0; r < 8; ++r) { \
                    const f32x4 a4 = *(const f32x4*)(a_lds + r * AST + m0 + (MI4)); \
                    vfma(acc[r], a4.x, hv[(MI4) + 0]); \
                    vfma(acc[r], a4.y, hv[(MI4) + 1]); \
                    vfma(acc[r], a4.z, hv[(MI4) + 2]); \
                    vfma(acc[r], a4.w, hv[(MI4) + 3]); \
                } \
            }
            // NOTE: up to 4 older prefetch loads may still be outstanding;
            // vmcnt(12) therefore also covers them before hv[0..3] (oldest-first).
            asm volatile("s_waitcnt vmcnt(12)" ::: "memory");
            __builtin_amdgcn_sched_barrier(0);
            AH_CHUNK(0)
            asm volatile("s_waitcnt vmcnt(8)" ::: "memory");
            __builtin_amdgcn_sched_barrier(0);
            AH_CHUNK(4)
            asm volatile("s_waitcnt vmcnt(4)" ::: "memory");
            __builtin_amdgcn_sched_barrier(0);
            AH_CHUNK(8)
            asm volatile("s_waitcnt vmcnt(0)" ::: "memory");
            __builtin_amdgcn_sched_barrier(0);
            AH_CHUNK(12)
#undef AH_CHUNK
            #pragma unroll
            for (int r = 0; r < 8; ++r) {
                acc[r].x += __shfl_xor(acc[r].x, 16); acc[r].y += __shfl_xor(acc[r].y, 16);
                acc[r].z += __shfl_xor(acc[r].z, 16); acc[r].w += __shfl_xor(acc[r].w, 16);
                acc[r].x += __shfl_xor(acc[r].x, 32); acc[r].y += __shfl_xor(acc[r].y, 32);
                acc[r].z += __shfl_xor(acc[r].z, 32); acc[r].w += __shfl_xor(acc[r].w, 32);
            }
            if ((tid & 48) == 0) {
                const int w = tid >> 6;
                #pragma unroll
                for (int r = 0; r < 8; ++r)
                    *(f32x4*)(u_lds + w * AHWS + r * 64 + c4) = acc[r];
            }
        }
        __syncthreads();   // barrier A

        // reduce wave partials -> ah_lds / ax_s
        {
            float s = 0.f;
            #pragma unroll
            for (int w2 = 0; w2 < 8; ++w2) s += u_lds[w2 * AHWS + tid];
            ah_lds[tid] = s;
            if (tid < 64) {
                float s2 = 0.f;
                #pragma unroll
                for (int w2 = 0; w2 < 8; ++w2) s2 += ax_part[w2 * 64 + tid];
                ax_s[tid] = s2;
            }
        }
        __syncthreads();   // barrier B

        // phase B: g[r][jj] = ah@Wh + ax@Wx + b (36 / 28+8 split over halves)
        {
            float g[8];
            #pragma unroll
            for (int r = 0; r < 8; ++r) g[r] = bias;
            if (half == 0) {
                #pragma unroll
                for (int k4 = 0; k4 < 36; k4 += 4) {
                    #pragma unroll
                    for (int r = 0; r < 8; ++r) {
                        const f32x4 a4 = *(const f32x4*)(ah_lds + r * 64 + k4);
                        g[r] = fmaf(a4.x, whcol[k4 + 0], g[r]);
                        g[r] = fmaf(a4.y, whcol[k4 + 1], g[r]);
                        g[r] = fmaf(a4.z, whcol[k4 + 2], g[r]);
                        g[r] = fmaf(a4.w, whcol[k4 + 3], g[r]);
                    }
                }
            } else {
                #pragma unroll
                for (int k4 = 0; k4 < 28; k4 += 4) {
                    #pragma unroll
                    for (int r = 0; r < 8; ++r) {
                        const f32x4 a4 = *(const f32x4*)(ah_lds + r * 64 + 36 + k4);
                        g[r] = fmaf(a4.x, whcol[k4 + 0], g[r]);
                        g[r] = fmaf(a4.y, whcol[k4 + 1], g[r]);
                        g[r] = fmaf(a4.z, whcol[k4 + 2], g[r]);
                        g[r] = fmaf(a4.w, whcol[k4 + 3], g[r]);
                    }
                }
                #pragma unroll
                for (int d4 = 0; d4 < 8; d4 += 4) {
                    #pragma unroll
                    for (int r = 0; r < 8; ++r) {
                        const f32x4 a4 = *(const f32x4*)(ax_s + r * 8 + d4);
                        g[r] = fmaf(a4.x, whcol[28 + d4 + 0], g[r]);
                        g[r] = fmaf(a4.y, whcol[28 + d4 + 1], g[r]);
                        g[r] = fmaf(a4.z, whcol[28 + d4 + 2], g[r]);
                        g[r] = fmaf(a4.w, whcol[28 + d4 + 3], g[r]);
                    }
                }
            }
            #pragma unroll
            for (int r = 0; r < 8; ++r) u_lds[(half * 8 + r) * 256 + jj] = g[r];
        }
        __syncthreads();   // barrier C

        // gates + state update
        float hn;
        {
            const float gi = u_lds[r_g * 256 + j_g]       + u_lds[(8 + r_g) * 256 + j_g];
            const float gf = u_lds[r_g * 256 + 64 + j_g]  + u_lds[(8 + r_g) * 256 + 64 + j_g];
            const float go = u_lds[r_g * 256 + 128 + j_g] + u_lds[(8 + r_g) * 256 + 128 + j_g];
            const float gg = u_lds[r_g * 256 + 192 + j_g] + u_lds[(8 + r_g) * 256 + 192 + j_g];
            const float ig = sigm_f(gi);
            const float fg = sigm_f(gf);
            const float og = sigm_f(go);
            const float gt = tanh_f(gg);
            c_reg = fg * c_reg + ig * gt;
            hn = og * tanh_f(c_reg);
        }
        if (t == SS - 1) {
            if (slot == 0 && tid < 64) hh_s[tid] = hn;   // wave 0 owns node 0
            break;
        }
        // write-through h store (issue only; drain overlapped with staging)
        {
            const unsigned long long haddr = (unsigned long long)(const void*)(hd + sidx);
            asm volatile("global_store_dword %0, %1, off sc0 sc1"
                         :: "v"(haddr), "v"(hn) : "memory");
        }

        // stage t+1 LDS from regs (h-independent; no wave still reads a/x_lds)
        {
            const int f0 = tid * 4;
            *(float4*)(a_lds + (f0 >> 9) * AST + (f0 & 511)) = qa0;
            const int f1 = 2048 + tid * 4;
            *(float4*)(a_lds + (f1 >> 9) * AST + (f1 & 511)) = qa1;
            *(float4*)(x_lds + tid * 4) = qx0;
            *(float4*)(x_lds + 2048 + tid * 4) = qx1;
        }
        // drain the write-through store (overlapped with the LDS staging above)
        asm volatile("s_waitcnt vmcnt(0)" ::: "memory");
        __syncthreads();   // staging done + all h stores at the coherence point

        // arrive EARLY (tid0): relaxed tree arrival, no fences
        if (tid == 0) {
            const unsigned tgt = 8u * (unsigned)(t + 1);
            unsigned lo = __hip_atomic_fetch_add(bgrp, 1u, __ATOMIC_RELAXED, __HIP_MEMORY_SCOPE_AGENT);
            if (lo == tgt - 1u)
                __hip_atomic_fetch_add(broot, 1u, __ATOMIC_RELAXED, __HIP_MEMORY_SCOPE_AGENT);
        }

        // reg prefetch t+2 (lands during next step)
        {
            const int t2 = (t + 2 < SS) ? t + 2 : SS - 1;
            const float* ab = adj + (((size_t)b * SS + t2) * NN + n0) * NN;
            const float* xb = x + ((size_t)b * SS + t2) * (NN * DD);
            qa0 = *(const float4*)(ab + tid * 4);
            qa1 = *(const float4*)(ab + 2048 + tid * 4);
            qx0 = *(const float4*)(xb + tid * 4);
            qx1 = *(const float4*)(xb + 2048 + tid * 4);
        }

        // x-agg partials for t+1 (overlaps barrier latency)
        {
            const int d = tid & 7, rr = (tid >> 3) & 7, mg2 = tid >> 6;
            const float* ar = a_lds + rr * AST + mg2 * 64;
            const float* xr = x_lds + mg2 * 512 + d;
            float s = 0.f;
            #pragma unroll
            for (int mi = 0; mi < 64; ++mi) s = fmaf(ar[mi], xr[mi * 8], s);
            ax_part[tid] = s;
        }

        // poll LATE (tid0): root counter directly (8 leaf-completions/step)
        if (tid == 0) {
            const unsigned tgt = 8u * (unsigned)(t + 1);
            while (__hip_atomic_load(broot, __ATOMIC_RELAXED, __HIP_MEMORY_SCOPE_AGENT) < tgt)
                __builtin_amdgcn_s_sleep(1);
        }
        // all producers' stores are in IC now; drop (clean) stale L2 lines so
        // next step's sc0 h-loads see fresh data via this XCD's L2.
        if (tid < 64)
            asm volatile("buffer_inv sc1" ::: "memory");
        __syncthreads();
        __builtin_amdgcn_sched_barrier(0);

        hp = hd;
        hd = (hd == hA) ? hB : hA;
    }

    // ---- per-batch readout head (block owning node 0 of each batch) ------
    if (slot == 0) {
        __syncthreads();
        if (tid < 32) {
            float s = b1[tid];
            #pragma unroll
            for (int j = 0; j < 64; ++j) s = fmaf(hh_s[j], W1[j * 32 + tid], s);
            z1_s[tid] = fmaxf(s, 0.f);
        }
        __syncthreads();
        if (tid < OUTK) {
            float s = b2[tid];
            #pragma unroll
            for (int k = 0; k < 32; ++k) s = fmaf(z1_s[k], W2[k * 24 + tid], s);
            out[b * OUTK + tid] = s;
        }
    }
}

// ---------------------------------------------------------------------------
extern "C" void kernel_launch(void* const* d_in, const int* in_sizes, int n_in,
                              void* d_out, int out_size, void* d_ws, size_t ws_size,
                              hipStream_t stream) {
    const float* x   = (const float*)d_in[0];
    const float* adj = (const float*)d_in[1];
    const float* h0  = (const float*)d_in[2];
    const float* c0  = (const float*)d_in[3];
    const float* Wx  = (const float*)d_in[4];
    const float* Wh  = (const float*)d_in[5];
    const float* bg  = (const float*)d_in[6];
    const float* W1  = (const float*)d_in[7];
    const float* b1  = (const float*)d_in[8];
    const float* W2  = (const float*)d_in[9];
    const float* b2  = (const float*)d_in[10];
    float* out = (float*)d_out;

    const int NE = BB * NN * HH;              // 131072 floats per h buffer
    float* ws = (float*)d_ws;
    float* hA = ws;
    float* hB = ws + NE;
    unsigned* bar = (unsigned*)(ws + 2 * NE);

    bar_init<<<(BB * BSTR + 255) / 256, 256, 0, stream>>>(bar);

    void* args[] = { (void*)&x, (void*)&adj, (void*)&h0, (void*)&c0,
                     (void*)&Wx, (void*)&Wh, (void*)&bg,
                     (void*)&W1, (void*)&b1, (void*)&W2, (void*)&b2,
                     (void*)&out, (void*)&hA, (void*)&hB, (void*)&bar };
    hipLaunchCooperativeKernel((void*)gnn_lstm_persist,
                               dim3(NBLK), dim3(THREADS), args, 0, stream);
}

// Round 2
// 940.352 us; speedup vs baseline: 1.0567x; 1.0567x over previous
//
#include <hip/hip_runtime.h>
#include <math.h>

// Problem constants
#define BB   4
#define SS   96
#define NN   512
#define DD   8
#define HH   64
#define G4   256    // 4*H
#define OUTK 24

#define THREADS 512
#define NBLK    256   // 4 batches x 64 blocks, cooperative (co-resident, 1/CU)
#define RPB     8     // adj rows per block
#define AST     580   // a_lds row stride
#define AHWS    516   // u_lds per-wave stride
#define ITEM    64    // u32 per barrier slot (256 B)
#define BSTR    (10 * ITEM)   // per-batch barrier stride: 8 leaf + root + spare
#define XELO    (BB * BSTR)             // xelect[8] base (leader election)
#define XFLO    (BB * BSTR + 8 * ITEM)  // xflag[8] base (per-XCD release)
#define BARSZ   (BB * BSTR + 16 * ITEM)

typedef float f32x4 __attribute__((ext_vector_type(4)));

// ---------------------------------------------------------------------------
__global__ void bar_init(unsigned* __restrict__ bar) {
    const int i = blockIdx.x * 256 + threadIdx.x;
    if (i < BARSZ) bar[i] = 0u;
}

__device__ __forceinline__ float sigm_f(float v) { return 1.f / (1.f + __expf(-v)); }
__device__ __forceinline__ float tanh_f(float v) { return 1.f - 2.f / (__expf(2.f * v) + 1.f); }

__device__ __forceinline__ void vfma(f32x4& d, float s, f32x4 v) {
    d.x = fmaf(s, v.x, d.x); d.y = fmaf(s, v.y, d.y);
    d.z = fmaf(s, v.z, d.z); d.w = fmaf(s, v.w, d.w);
}

// ---------------------------------------------------------------------------
__global__ __launch_bounds__(THREADS, 2) void gnn_lstm_persist(
    const float* __restrict__ x,    // [B][S][N][D]
    const float* __restrict__ adj,  // [B][S][N][N]
    const float* __restrict__ h0,   // [B][N][H]
    const float* __restrict__ c0,   // [B][N][H]
    const float* __restrict__ Wx,   // [D][256]
    const float* __restrict__ Wh,   // [H][256]
    const float* __restrict__ bg,   // [256]
    const float* __restrict__ W1, const float* __restrict__ b1,
    const float* __restrict__ W2, const float* __restrict__ b2,
    float* __restrict__ out,        // [4][24]
    float* __restrict__ hA, float* __restrict__ hB,
    unsigned* __restrict__ bar)
{
    __shared__ float a_lds[RPB * AST];   // adj tile (stride-swizzled)
    __shared__ float x_lds[NN * DD];     // x slice
    __shared__ float u_lds[8 * AHWS];    // union: ah wave-partials | g partials
    __shared__ float ax_part[THREADS];
    __shared__ float ah_lds[RPB * HH];
    __shared__ float ax_s[RPB * DD];
    __shared__ float hh_s[HH];
    __shared__ float z1_s[32];

    const int tid  = threadIdx.x;
    const int bid  = blockIdx.x;
    const int b    = bid >> 6;           // batch
    const int slot = bid & 63;           // 0..63 within batch
    const int n0   = slot * RPB;
    const int r_g  = tid >> 6;           // wave id = owned row
    const int j_g  = tid & 63;

    // per-batch tree barrier (all atomics RELAXED; data travels via IC)
    unsigned* const bgrp  = bar + b * BSTR + (bid & 7) * ITEM;  // leaf: 8 members
    unsigned* const broot = bar + b * BSTR + 8 * ITEM;

    // per-XCD leader + release flag (one buffer_inv per XCD per step)
    unsigned xcc;
    asm("s_getreg_b32 %0, hwreg(HW_REG_XCC_ID)" : "=s"(xcc));
    unsigned* const xelect = bar + XELO + (int)xcc * ITEM;
    unsigned* const xflag  = bar + XFLO + (int)xcc * ITEM;

    // ---- persistent per-thread state -------------------------------------
    const int half = tid >> 8;           // 0/1
    const int jj   = tid & 255;          // gate column
    float whcol[36];
    if (half == 0) {
        #pragma unroll
        for (int k = 0; k < 36; ++k) whcol[k] = Wh[k * G4 + jj];
    } else {
        #pragma unroll
        for (int k = 0; k < 28; ++k) whcol[k] = Wh[(36 + k) * G4 + jj];
        #pragma unroll
        for (int d = 0; d < 8; ++d)  whcol[28 + d] = Wx[d * G4 + jj];
    }
    const float bias = (half == 0) ? bg[jj] : 0.f;
    const size_t sidx = ((size_t)b * NN + n0 + r_g) * HH + j_g;
    float c_reg = c0[sidx];

    // leader election (once): first block to claim its XCD's slot
    unsigned am_lead = 0;
    if (tid == 0)
        am_lead = (__hip_atomic_fetch_add(xelect, 1u, __ATOMIC_RELAXED,
                                          __HIP_MEMORY_SCOPE_AGENT) == 0u);

    // ---- stage adj(0), x(0) ----------------------------------------------
    {
        const float* ab = adj + (((size_t)b * SS + 0) * NN + n0) * NN;
        const float* xb = x + ((size_t)b * SS + 0) * (NN * DD);
        float4 pa0 = *(const float4*)(ab + tid * 4);
        float4 pa1 = *(const float4*)(ab + 2048 + tid * 4);
        float4 px0 = *(const float4*)(xb + tid * 4);
        float4 px1 = *(const float4*)(xb + 2048 + tid * 4);
        const int f0 = tid * 4;
        *(float4*)(a_lds + (f0 >> 9) * AST + (f0 & 511)) = pa0;
        const int f1 = 2048 + tid * 4;
        *(float4*)(a_lds + (f1 >> 9) * AST + (f1 & 511)) = pa1;
        *(float4*)(x_lds + tid * 4) = px0;
        *(float4*)(x_lds + 2048 + tid * 4) = px1;
    }
    __syncthreads();

    // ---- reg prefetch t=1 ----
    float4 qa0, qa1, qx0, qx1;
    {
        const float* ab = adj + (((size_t)b * SS + 1) * NN + n0) * NN;
        const float* xb = x + ((size_t)b * SS + 1) * (NN * DD);
        qa0 = *(const float4*)(ab + tid * 4);
        qa1 = *(const float4*)(ab + 2048 + tid * 4);
        qx0 = *(const float4*)(xb + tid * 4);
        qx1 = *(const float4*)(xb + 2048 + tid * 4);
    }

    // ---- x-agg partials for t=0 ----
    {
        const int d = tid & 7, rr = (tid >> 3) & 7, mg2 = tid >> 6;
        const float* ar = a_lds + rr * AST + mg2 * 64;
        const float* xr = x_lds + mg2 * 512 + d;
        float s = 0.f;
        #pragma unroll
        for (int mi = 0; mi < 64; ++mi) s = fmaf(ar[mi], xr[mi * 8], s);
        ax_part[tid] = s;
    }

    const float* hp = h0;
    float* hd = hB;

    const int c4 = (tid & 15) * 4;
    const int m0 = (tid >> 4) * 16;

    // ---- main recurrence -------------------------------------------------
    for (int t = 0; t < SS; ++t) {
        // phase A: 16 h-row loads, L1-bypass only (sc0). The per-XCD L2 was
        // flash-invalidated exactly ONCE (by the XCD leader) after all stores
        // of the previous step reached IC, so L2 serves fresh data and each
        // h line is IC-fetched once per XCD, then shared by 32 blocks.
        f32x4 hv[16];
        {
            const float* hpb = hp + (size_t)b * NN * HH;
            const unsigned long long hbase =
                (unsigned long long)(const void*)(hpb + (size_t)m0 * HH + c4);
#define HLOAD(I, OFFS) \
            asm volatile("global_load_dwordx4 %0, %1, off offset:" OFFS " sc0" \
                         : "=v"(hv[I]) : "v"(hbase) : "memory")
            HLOAD(0, "0");     HLOAD(1, "256");   HLOAD(2, "512");   HLOAD(3, "768");
            HLOAD(4, "1024");  HLOAD(5, "1280");  HLOAD(6, "1536");  HLOAD(7, "1792");
            HLOAD(8, "2048");  HLOAD(9, "2304");  HLOAD(10, "2560"); HLOAD(11, "2816");
            HLOAD(12, "3072"); HLOAD(13, "3328"); HLOAD(14, "3584"); HLOAD(15, "3840");
#undef HLOAD
        }
        // per-thread 8-row x 4-col tile, pipelined against the load burst
        {
            f32x4 acc[8];
            #pragma unroll
            for (int r = 0; r < 8; ++r) acc[r] = f32x4{0.f, 0.f, 0.f, 0.f};
#define AH_CHUNK(MI4) \
            { \
                _Pragma("unroll") \
                for (int r = 0; r < 8; ++r) { \
                    const f32x4 a4 = *(const f32x4*)(a_lds + r * AST + m0 + (MI4)); \
                    vfma(acc[r], a4.x, hv[(MI4) + 0]); \
                    vfma(acc[r], a4.y, hv[(MI4) + 1]); \
                    vfma(acc[r], a4.z, hv[(MI4) + 2]); \
                    vfma(acc[r], a4.w, hv[(MI4) + 3]); \
                } \
            }
            // NOTE: up to 4 older prefetch loads may still be outstanding;
            // vmcnt(12) therefore also covers them before hv[0..3] (oldest-first).
            asm volatile("s_waitcnt vmcnt(12)" ::: "memory");
            __builtin_amdgcn_sched_barrier(0);
            AH_CHUNK(0)
            asm volatile("s_waitcnt vmcnt(8)" ::: "memory");
            __builtin_amdgcn_sched_barrier(0);
            AH_CHUNK(4)
            asm volatile("s_waitcnt vmcnt(4)" ::: "memory");
            __builtin_amdgcn_sched_barrier(0);
            AH_CHUNK(8)
            asm volatile("s_waitcnt vmcnt(0)" ::: "memory");
            __builtin_amdgcn_sched_barrier(0);
            AH_CHUNK(12)
#undef AH_CHUNK
            #pragma unroll
            for (int r = 0; r < 8; ++r) {
                acc[r].x += __shfl_xor(acc[r].x, 16); acc[r].y += __shfl_xor(acc[r].y, 16);
                acc[r].z += __shfl_xor(acc[r].z, 16); acc[r].w += __shfl_xor(acc[r].w, 16);
                acc[r].x += __shfl_xor(acc[r].x, 32); acc[r].y += __shfl_xor(acc[r].y, 32);
                acc[r].z += __shfl_xor(acc[r].z, 32); acc[r].w += __shfl_xor(acc[r].w, 32);
            }
            if ((tid & 48) == 0) {
                const int w = tid >> 6;
                #pragma unroll
                for (int r = 0; r < 8; ++r)
                    *(f32x4*)(u_lds + w * AHWS + r * 64 + c4) = acc[r];
            }
        }
        __syncthreads();   // barrier A

        // reduce wave partials -> ah_lds / ax_s
        {
            float s = 0.f;
            #pragma unroll
            for (int w2 = 0; w2 < 8; ++w2) s += u_lds[w2 * AHWS + tid];
            ah_lds[tid] = s;
            if (tid < 64) {
                float s2 = 0.f;
                #pragma unroll
                for (int w2 = 0; w2 < 8; ++w2) s2 += ax_part[w2 * 64 + tid];
                ax_s[tid] = s2;
            }
        }
        __syncthreads();   // barrier B

        // phase B: g[r][jj] = ah@Wh + ax@Wx + b (36 / 28+8 split over halves)
        {
            float g[8];
            #pragma unroll
            for (int r = 0; r < 8; ++r) g[r] = bias;
            if (half == 0) {
                #pragma unroll
                for (int k4 = 0; k4 < 36; k4 += 4) {
                    #pragma unroll
                    for (int r = 0; r < 8; ++r) {
                        const f32x4 a4 = *(const f32x4*)(ah_lds + r * 64 + k4);
                        g[r] = fmaf(a4.x, whcol[k4 + 0], g[r]);
                        g[r] = fmaf(a4.y, whcol[k4 + 1], g[r]);
                        g[r] = fmaf(a4.z, whcol[k4 + 2], g[r]);
                        g[r] = fmaf(a4.w, whcol[k4 + 3], g[r]);
                    }
                }
            } else {
                #pragma unroll
                for (int k4 = 0; k4 < 28; k4 += 4) {
                    #pragma unroll
                    for (int r = 0; r < 8; ++r) {
                        const f32x4 a4 = *(const f32x4*)(ah_lds + r * 64 + 36 + k4);
                        g[r] = fmaf(a4.x, whcol[k4 + 0], g[r]);
                        g[r] = fmaf(a4.y, whcol[k4 + 1], g[r]);
                        g[r] = fmaf(a4.z, whcol[k4 + 2], g[r]);
                        g[r] = fmaf(a4.w, whcol[k4 + 3], g[r]);
                    }
                }
                #pragma unroll
                for (int d4 = 0; d4 < 8; d4 += 4) {
                    #pragma unroll
                    for (int r = 0; r < 8; ++r) {
                        const f32x4 a4 = *(const f32x4*)(ax_s + r * 8 + d4);
                        g[r] = fmaf(a4.x, whcol[28 + d4 + 0], g[r]);
                        g[r] = fmaf(a4.y, whcol[28 + d4 + 1], g[r]);
                        g[r] = fmaf(a4.z, whcol[28 + d4 + 2], g[r]);
                        g[r] = fmaf(a4.w, whcol[28 + d4 + 3], g[r]);
                    }
                }
            }
            #pragma unroll
            for (int r = 0; r < 8; ++r) u_lds[(half * 8 + r) * 256 + jj] = g[r];
        }
        __syncthreads();   // barrier C

        // gates + state update
        float hn;
        {
            const float gi = u_lds[r_g * 256 + j_g]       + u_lds[(8 + r_g) * 256 + j_g];
            const float gf = u_lds[r_g * 256 + 64 + j_g]  + u_lds[(8 + r_g) * 256 + 64 + j_g];
            const float go = u_lds[r_g * 256 + 128 + j_g] + u_lds[(8 + r_g) * 256 + 128 + j_g];
            const float gg = u_lds[r_g * 256 + 192 + j_g] + u_lds[(8 + r_g) * 256 + 192 + j_g];
            const float ig = sigm_f(gi);
            const float fg = sigm_f(gf);
            const float og = sigm_f(go);
            const float gt = tanh_f(gg);
            c_reg = fg * c_reg + ig * gt;
            hn = og * tanh_f(c_reg);
        }
        if (t == SS - 1) {
            if (slot == 0 && tid < 64) hh_s[tid] = hn;   // wave 0 owns node 0
            break;
        }
        // write-through h store (issue only; drain overlapped with staging)
        {
            const unsigned long long haddr = (unsigned long long)(const void*)(hd + sidx);
            asm volatile("global_store_dword %0, %1, off sc0 sc1"
                         :: "v"(haddr), "v"(hn) : "memory");
        }

        // stage t+1 LDS from regs (h-independent; no wave still reads a/x_lds)
        {
            const int f0 = tid * 4;
            *(float4*)(a_lds + (f0 >> 9) * AST + (f0 & 511)) = qa0;
            const int f1 = 2048 + tid * 4;
            *(float4*)(a_lds + (f1 >> 9) * AST + (f1 & 511)) = qa1;
            *(float4*)(x_lds + tid * 4) = qx0;
            *(float4*)(x_lds + 2048 + tid * 4) = qx1;
        }
        // drain the write-through store (overlapped with the LDS staging above)
        asm volatile("s_waitcnt vmcnt(0)" ::: "memory");
        __syncthreads();   // staging done + all h stores at the coherence point

        // arrive EARLY (tid0): relaxed tree arrival, no fences
        if (tid == 0) {
            const unsigned tgt = 8u * (unsigned)(t + 1);
            unsigned lo = __hip_atomic_fetch_add(bgrp, 1u, __ATOMIC_RELAXED, __HIP_MEMORY_SCOPE_AGENT);
            if (lo == tgt - 1u)
                __hip_atomic_fetch_add(broot, 1u, __ATOMIC_RELAXED, __HIP_MEMORY_SCOPE_AGENT);
        }

        // reg prefetch t+2 (lands during next step; read-only data, inv-safe)
        {
            const int t2 = (t + 2 < SS) ? t + 2 : SS - 1;
            const float* ab = adj + (((size_t)b * SS + t2) * NN + n0) * NN;
            const float* xb = x + ((size_t)b * SS + t2) * (NN * DD);
            qa0 = *(const float4*)(ab + tid * 4);
            qa1 = *(const float4*)(ab + 2048 + tid * 4);
            qx0 = *(const float4*)(xb + tid * 4);
            qx1 = *(const float4*)(xb + 2048 + tid * 4);
        }

        // x-agg partials for t+1 (overlaps barrier latency)
        {
            const int d = tid & 7, rr = (tid >> 3) & 7, mg2 = tid >> 6;
            const float* ar = a_lds + rr * AST + mg2 * 64;
            const float* xr = x_lds + mg2 * 512 + d;
            float s = 0.f;
            #pragma unroll
            for (int mi = 0; mi < 64; ++mi) s = fmaf(ar[mi], xr[mi * 8], s);
            ax_part[tid] = s;
        }

        // release: leader waits ALL batches' roots -> one buffer_inv for this
        // XCD -> publish xflag. Followers wait xflag only (implies all roots).
        if (tid == 0) {
            const unsigned tgt = 8u * (unsigned)(t + 1);
            if (am_lead) {
                for (;;) {
                    unsigned ok = 1u;
                    #pragma unroll
                    for (int b2 = 0; b2 < BB; ++b2)
                        ok &= (unsigned)(__hip_atomic_load(bar + b2 * BSTR + 8 * ITEM,
                                 __ATOMIC_RELAXED, __HIP_MEMORY_SCOPE_AGENT) >= tgt);
                    if (ok) break;
                    __builtin_amdgcn_s_sleep(1);
                }
                // all h stores of step t are in IC; drop stale clean L2 lines
                asm volatile("buffer_inv sc1" ::: "memory");
                asm volatile("s_waitcnt vmcnt(0)" ::: "memory");
                __hip_atomic_store(xflag, (unsigned)(t + 1), __ATOMIC_RELAXED,
                                   __HIP_MEMORY_SCOPE_AGENT);
            } else {
                while (__hip_atomic_load(xflag, __ATOMIC_RELAXED,
                                         __HIP_MEMORY_SCOPE_AGENT) < (unsigned)(t + 1))
                    __builtin_amdgcn_s_sleep(1);
            }
        }
        __syncthreads();
        __builtin_amdgcn_sched_barrier(0);

        hp = hd;
        hd = (hd == hA) ? hB : hA;
    }

    // ---- per-batch readout head (block owning node 0 of each batch) ------
    if (slot == 0) {
        __syncthreads();
        if (tid < 32) {
            float s = b1[tid];
            #pragma unroll
            for (int j = 0; j < 64; ++j) s = fmaf(hh_s[j], W1[j * 32 + tid], s);
            z1_s[tid] = fmaxf(s, 0.f);
        }
        __syncthreads();
        if (tid < OUTK) {
            float s = b2[tid];
            #pragma unroll
            for (int k = 0; k < 32; ++k) s = fmaf(z1_s[k], W2[k * 24 + tid], s);
            out[b * OUTK + tid] = s;
        }
    }
}

// ---------------------------------------------------------------------------
extern "C" void kernel_launch(void* const* d_in, const int* in_sizes, int n_in,
                              void* d_out, int out_size, void* d_ws, size_t ws_size,
                              hipStream_t stream) {
    const float* x   = (const float*)d_in[0];
    const float* adj = (const float*)d_in[1];
    const float* h0  = (const float*)d_in[2];
    const float* c0  = (const float*)d_in[3];
    const float* Wx  = (const float*)d_in[4];
    const float* Wh  = (const float*)d_in[5];
    const float* bg  = (const float*)d_in[6];
    const float* W1  = (const float*)d_in[7];
    const float* b1  = (const float*)d_in[8];
    const float* W2  = (const float*)d_in[9];
    const float* b2  = (const float*)d_in[10];
    float* out = (float*)d_out;

    const int NE = BB * NN * HH;              // 131072 floats per h buffer
    float* ws = (float*)d_ws;
    float* hA = ws;
    float* hB = ws + NE;
    unsigned* bar = (unsigned*)(ws + 2 * NE);

    bar_init<<<(BARSZ + 255) / 256, 256, 0, stream>>>(bar);

    void* args[] = { (void*)&x, (void*)&adj, (void*)&h0, (void*)&c0,
                     (void*)&Wx, (void*)&Wh, (void*)&bg,
                     (void*)&W1, (void*)&b1, (void*)&W2, (void*)&b2,
                     (void*)&out, (void*)&hA, (void*)&hB, (void*)&bar };
    hipLaunchCooperativeKernel((void*)gnn_lstm_persist,
                               dim3(NBLK), dim3(THREADS), args, 0, stream);
}

// Round 6
// 806.938 us; speedup vs baseline: 1.2314x; 1.1653x over previous
//
#include <hip/hip_runtime.h>
#include <math.h>

// Problem constants
#define BB   4
#define SS   96
#define NN   512
#define DD   8
#define HH   64
#define G4   256    // 4*H
#define OUTK 24

#define THREADS 512
#define NBLK    256   // 4 batches x 64 blocks, cooperative (co-resident, 1/CU)
#define RPB     8     // adj rows per block
#define AST     580   // a_lds row stride
#define AHWS    516   // u_lds per-wave stride
#define CSTR    64    // u32 stride per batch counter (256 B, own cacheline)
#define BARSZ   (BB * CSTR)

typedef float f32x4 __attribute__((ext_vector_type(4)));

// ---------------------------------------------------------------------------
__global__ void bar_init(unsigned* __restrict__ bar) {
    const int i = blockIdx.x * 256 + threadIdx.x;
    if (i < BARSZ) bar[i] = 0u;
}

__device__ __forceinline__ float sigm_f(float v) { return 1.f / (1.f + __expf(-v)); }
__device__ __forceinline__ float tanh_f(float v) { return 1.f - 2.f / (__expf(2.f * v) + 1.f); }

__device__ __forceinline__ void vfma(f32x4& d, float s, f32x4 v) {
    d.x = fmaf(s, v.x, d.x); d.y = fmaf(s, v.y, d.y);
    d.z = fmaf(s, v.z, d.z); d.w = fmaf(s, v.w, d.w);
}

// ---------------------------------------------------------------------------
__global__ __launch_bounds__(THREADS, 2) void gnn_lstm_persist(
    const float* __restrict__ x,    // [B][S][N][D]
    const float* __restrict__ adj,  // [B][S][N][N]
    const float* __restrict__ h0,   // [B][N][H]
    const float* __restrict__ c0,   // [B][N][H]
    const float* __restrict__ Wx,   // [D][256]
    const float* __restrict__ Wh,   // [H][256]
    const float* __restrict__ bg,   // [256]
    const float* __restrict__ W1, const float* __restrict__ b1,
    const float* __restrict__ W2, const float* __restrict__ b2,
    float* __restrict__ out,        // [4][24]
    float* __restrict__ hA, float* __restrict__ hB,
    unsigned* __restrict__ bar)
{
    __shared__ float a_lds[RPB * AST];   // adj tile (stride-swizzled)
    __shared__ float x_lds[NN * DD];     // x slice
    __shared__ float u_lds[8 * AHWS];    // union: ah wave-partials | g partials
    __shared__ float ax_part[THREADS];
    __shared__ float ah_lds[RPB * HH];
    __shared__ float ax_s[RPB * DD];
    __shared__ float hh_s[HH];
    __shared__ float z1_s[32];

    const int tid  = threadIdx.x;
    const int bid  = blockIdx.x;
    const int b    = bid >> 6;           // batch
    const int slot = bid & 63;           // 0..63 within batch
    const int n0   = slot * RPB;
    const int r_g  = tid >> 6;           // wave id = owned row
    const int j_g  = tid & 63;

    // flat per-batch arrival counter (monotonic, relaxed, fire-and-forget add)
    unsigned* const broot = bar + b * CSTR;

    // ---- persistent per-thread state -------------------------------------
    const int half = tid >> 8;           // 0/1
    const int jj   = tid & 255;          // gate column
    float whcol[36];
    if (half == 0) {
        #pragma unroll
        for (int k = 0; k < 36; ++k) whcol[k] = Wh[k * G4 + jj];
    } else {
        #pragma unroll
        for (int k = 0; k < 28; ++k) whcol[k] = Wh[(36 + k) * G4 + jj];
        #pragma unroll
        for (int d = 0; d < 8; ++d)  whcol[28 + d] = Wx[d * G4 + jj];
    }
    const float bias = (half == 0) ? bg[jj] : 0.f;
    const size_t sidx = ((size_t)b * NN + n0 + r_g) * HH + j_g;
    float c_reg = c0[sidx];

    // ---- stage adj(0), x(0) ----------------------------------------------
    {
        const float* ab = adj + (((size_t)b * SS + 0) * NN + n0) * NN;
        const float* xb = x + ((size_t)b * SS + 0) * (NN * DD);
        f32x4 pa0 = *(const f32x4*)(ab + tid * 4);
        f32x4 pa1 = *(const f32x4*)(ab + 2048 + tid * 4);
        f32x4 px0 = *(const f32x4*)(xb + tid * 4);
        f32x4 px1 = *(const f32x4*)(xb + 2048 + tid * 4);
        const int f0 = tid * 4;
        *(f32x4*)(a_lds + (f0 >> 9) * AST + (f0 & 511)) = pa0;
        const int f1 = 2048 + tid * 4;
        *(f32x4*)(a_lds + (f1 >> 9) * AST + (f1 & 511)) = pa1;
        *(f32x4*)(x_lds + tid * 4) = px0;
        *(f32x4*)(x_lds + 2048 + tid * 4) = px1;
    }
    __syncthreads();

    // ---- reg prefetch t=1 ----
    f32x4 qa0, qa1, qx0, qx1;
    {
        const float* ab = adj + (((size_t)b * SS + 1) * NN + n0) * NN;
        const float* xb = x + ((size_t)b * SS + 1) * (NN * DD);
        qa0 = *(const f32x4*)(ab + tid * 4);
        qa1 = *(const f32x4*)(ab + 2048 + tid * 4);
        qx0 = *(const f32x4*)(xb + tid * 4);
        qx1 = *(const f32x4*)(xb + 2048 + tid * 4);
    }

    // ---- x-agg partials for t=0 ----
    {
        const int d = tid & 7, rr = (tid >> 3) & 7, mg2 = tid >> 6;
        const float* ar = a_lds + rr * AST + mg2 * 64;
        const float* xr = x_lds + mg2 * 512 + d;
        float s = 0.f;
        #pragma unroll
        for (int mi = 0; mi < 64; ++mi) s = fmaf(ar[mi], xr[mi * 8], s);
        ax_part[tid] = s;
    }

    const float* hp = h0;
    float* hd = hB;

    const int c4 = (tid & 15) * 4;
    const int m0 = (tid >> 4) * 16;

    // ---- main recurrence -------------------------------------------------
    for (int t = 0; t < SS; ++t) {
        // phase A: 16 h-row loads (IC-coherent), pipelined with FMA chunks
        f32x4 hv[16];
        {
            const float* hpb = hp + (size_t)b * NN * HH;
            const unsigned long long hbase =
                (unsigned long long)(const void*)(hpb + (size_t)m0 * HH + c4);
#define HLOAD(I, OFFS) \
            asm volatile("global_load_dwordx4 %0, %1, off offset:" OFFS " sc0 sc1" \
                         : "=v"(hv[I]) : "v"(hbase) : "memory")
            HLOAD(0, "0");     HLOAD(1, "256");   HLOAD(2, "512");   HLOAD(3, "768");
            HLOAD(4, "1024");  HLOAD(5, "1280");  HLOAD(6, "1536");  HLOAD(7, "1792");
            HLOAD(8, "2048");  HLOAD(9, "2304");  HLOAD(10, "2560"); HLOAD(11, "2816");
            HLOAD(12, "3072"); HLOAD(13, "3328"); HLOAD(14, "3584"); HLOAD(15, "3840");
#undef HLOAD
        }
        // per-thread 8-row x 4-col tile, pipelined against the load burst
        {
            f32x4 acc[8];
            #pragma unroll
            for (int r = 0; r < 8; ++r) acc[r] = f32x4{0.f, 0.f, 0.f, 0.f};
#define AH_CHUNK(MI4) \
            { \
                _Pragma("unroll") \
                for (int r = 0; r < 8; ++r) { \
                    const f32x4 a4 = *(const f32x4*)(a_lds + r * AST + m0 + (MI4)); \
                    vfma(acc[r], a4.x, hv[(MI4) + 0]); \
                    vfma(acc[r], a4.y, hv[(MI4) + 1]); \
                    vfma(acc[r], a4.z, hv[(MI4) + 2]); \
                    vfma(acc[r], a4.w, hv[(MI4) + 3]); \
                } \
            }
            // NOTE: up to 4 older prefetch loads may still be outstanding;
            // vmcnt(12) therefore also covers them before hv[0..3] (oldest-first).
            asm volatile("s_waitcnt vmcnt(12)" ::: "memory");
            __builtin_amdgcn_sched_barrier(0);
            AH_CHUNK(0)
            asm volatile("s_waitcnt vmcnt(8)" ::: "memory");
            __builtin_amdgcn_sched_barrier(0);
            AH_CHUNK(4)
            asm volatile("s_waitcnt vmcnt(4)" ::: "memory");
            __builtin_amdgcn_sched_barrier(0);
            AH_CHUNK(8)
            asm volatile("s_waitcnt vmcnt(0)" ::: "memory");
            __builtin_amdgcn_sched_barrier(0);
            AH_CHUNK(12)
#undef AH_CHUNK
            #pragma unroll
            for (int r = 0; r < 8; ++r) {
                acc[r].x += __shfl_xor(acc[r].x, 16); acc[r].y += __shfl_xor(acc[r].y, 16);
                acc[r].z += __shfl_xor(acc[r].z, 16); acc[r].w += __shfl_xor(acc[r].w, 16);
                acc[r].x += __shfl_xor(acc[r].x, 32); acc[r].y += __shfl_xor(acc[r].y, 32);
                acc[r].z += __shfl_xor(acc[r].z, 32); acc[r].w += __shfl_xor(acc[r].w, 32);
            }
            if ((tid & 48) == 0) {
                const int w = tid >> 6;
                #pragma unroll
                for (int r = 0; r < 8; ++r)
                    *(f32x4*)(u_lds + w * AHWS + r * 64 + c4) = acc[r];
            }
        }
        __syncthreads();   // barrier A

        // reduce wave partials -> ah_lds / ax_s
        {
            float s = 0.f;
            #pragma unroll
            for (int w2 = 0; w2 < 8; ++w2) s += u_lds[w2 * AHWS + tid];
            ah_lds[tid] = s;
            if (tid < 64) {
                float s2 = 0.f;
                #pragma unroll
                for (int w2 = 0; w2 < 8; ++w2) s2 += ax_part[w2 * 64 + tid];
                ax_s[tid] = s2;
            }
        }
        __syncthreads();   // barrier B

        // phase B: g[r][jj] = ah@Wh + ax@Wx + b (36 / 28+8 split over halves)
        {
            float g[8];
            #pragma unroll
            for (int r = 0; r < 8; ++r) g[r] = bias;
            if (half == 0) {
                #pragma unroll
                for (int k4 = 0; k4 < 36; k4 += 4) {
                    #pragma unroll
                    for (int r = 0; r < 8; ++r) {
                        const f32x4 a4 = *(const f32x4*)(ah_lds + r * 64 + k4);
                        g[r] = fmaf(a4.x, whcol[k4 + 0], g[r]);
                        g[r] = fmaf(a4.y, whcol[k4 + 1], g[r]);
                        g[r] = fmaf(a4.z, whcol[k4 + 2], g[r]);
                        g[r] = fmaf(a4.w, whcol[k4 + 3], g[r]);
                    }
                }
            } else {
                #pragma unroll
                for (int k4 = 0; k4 < 28; k4 += 4) {
                    #pragma unroll
                    for (int r = 0; r < 8; ++r) {
                        const f32x4 a4 = *(const f32x4*)(ah_lds + r * 64 + 36 + k4);
                        g[r] = fmaf(a4.x, whcol[k4 + 0], g[r]);
                        g[r] = fmaf(a4.y, whcol[k4 + 1], g[r]);
                        g[r] = fmaf(a4.z, whcol[k4 + 2], g[r]);
                        g[r] = fmaf(a4.w, whcol[k4 + 3], g[r]);
                    }
                }
                #pragma unroll
                for (int d4 = 0; d4 < 8; d4 += 4) {
                    #pragma unroll
                    for (int r = 0; r < 8; ++r) {
                        const f32x4 a4 = *(const f32x4*)(ax_s + r * 8 + d4);
                        g[r] = fmaf(a4.x, whcol[28 + d4 + 0], g[r]);
                        g[r] = fmaf(a4.y, whcol[28 + d4 + 1], g[r]);
                        g[r] = fmaf(a4.z, whcol[28 + d4 + 2], g[r]);
                        g[r] = fmaf(a4.w, whcol[28 + d4 + 3], g[r]);
                    }
                }
            }
            #pragma unroll
            for (int r = 0; r < 8; ++r) u_lds[(half * 8 + r) * 256 + jj] = g[r];
        }
        __syncthreads();   // barrier C

        // gates + state update
        float hn;
        {
            const float gi = u_lds[r_g * 256 + j_g]       + u_lds[(8 + r_g) * 256 + j_g];
            const float gf = u_lds[r_g * 256 + 64 + j_g]  + u_lds[(8 + r_g) * 256 + 64 + j_g];
            const float go = u_lds[r_g * 256 + 128 + j_g] + u_lds[(8 + r_g) * 256 + 128 + j_g];
            const float gg = u_lds[r_g * 256 + 192 + j_g] + u_lds[(8 + r_g) * 256 + 192 + j_g];
            const float ig = sigm_f(gi);
            const float fg = sigm_f(gf);
            const float og = sigm_f(go);
            const float gt = tanh_f(gg);
            c_reg = fg * c_reg + ig * gt;
            hn = og * tanh_f(c_reg);
        }
        if (t == SS - 1) {
            if (slot == 0 && tid < 64) hh_s[tid] = hn;   // wave 0 owns node 0
            break;
        }
        // write-through h store (issue only; drain overlapped with staging)
        {
            const unsigned long long haddr = (unsigned long long)(const void*)(hd + sidx);
            asm volatile("global_store_dword %0, %1, off sc0 sc1"
                         :: "v"(haddr), "v"(hn) : "memory");
        }

        // stage t+1 LDS from regs (no wave of this block still reads a/x_lds)
        {
            const int f0 = tid * 4;
            *(f32x4*)(a_lds + (f0 >> 9) * AST + (f0 & 511)) = qa0;
            const int f1 = 2048 + tid * 4;
            *(f32x4*)(a_lds + (f1 >> 9) * AST + (f1 & 511)) = qa1;
            *(f32x4*)(x_lds + tid * 4) = qx0;
            *(f32x4*)(x_lds + 2048 + tid * 4) = qx1;
        }
        // drain the write-through store (overlapped with the LDS staging above)
        asm volatile("s_waitcnt vmcnt(0)" ::: "memory");
        __syncthreads();   // staging done + all h stores of this block are in IC

        // arrive EARLY (tid0): single fire-and-forget relaxed add on the flat
        // per-batch counter (no dependent leaf->root chain, result unused)
        if (tid == 0)
            __hip_atomic_fetch_add(broot, 1u, __ATOMIC_RELAXED, __HIP_MEMORY_SCOPE_AGENT);

        // reg prefetch t+2 (lands during next step)
        {
            const int t2 = (t + 2 < SS) ? t + 2 : SS - 1;
            const float* ab = adj + (((size_t)b * SS + t2) * NN + n0) * NN;
            const float* xb = x + ((size_t)b * SS + t2) * (NN * DD);
            qa0 = *(const f32x4*)(ab + tid * 4);
            qa1 = *(const f32x4*)(ab + 2048 + tid * 4);
            qx0 = *(const f32x4*)(xb + tid * 4);
            qx1 = *(const f32x4*)(xb + 2048 + tid * 4);
        }

        // x-agg partials for t+1 (overlaps the arrival-propagation window)
        {
            const int d = tid & 7, rr = (tid >> 3) & 7, mg2 = tid >> 6;
            const float* ar = a_lds + rr * AST + mg2 * 64;
            const float* xr = x_lds + mg2 * 512 + d;
            float s = 0.f;
            #pragma unroll
            for (int mi = 0; mi < 64; ++mi) s = fmaf(ar[mi], xr[mi * 8], s);
            ax_part[tid] = s;
        }

        // poll LATE (tid0): one address, 64*(t+1) arrivals == all h(t) stored
        if (tid == 0) {
            const unsigned tgt = 64u * (unsigned)(t + 1);
            while (__hip_atomic_load(broot, __ATOMIC_RELAXED, __HIP_MEMORY_SCOPE_AGENT) < tgt)
                __builtin_amdgcn_s_sleep(1);
        }
        __syncthreads();
        __builtin_amdgcn_sched_barrier(0);

        hp = hd;
        hd = (hd == hA) ? hB : hA;
    }

    // ---- per-batch readout head (block owning node 0 of each batch) ------
    if (slot == 0) {
        __syncthreads();
        if (tid < 32) {
            float s = b1[tid];
            #pragma unroll
            for (int j = 0; j < 64; ++j) s = fmaf(hh_s[j], W1[j * 32 + tid], s);
            z1_s[tid] = fmaxf(s, 0.f);
        }
        __syncthreads();
        if (tid < OUTK) {
            float s = b2[tid];
            #pragma unroll
            for (int k = 0; k < 32; ++k) s = fmaf(z1_s[k], W2[k * 24 + tid], s);
            out[b * OUTK + tid] = s;
        }
    }
}

// ---------------------------------------------------------------------------
extern "C" void kernel_launch(void* const* d_in, const int* in_sizes, int n_in,
                              void* d_out, int out_size, void* d_ws, size_t ws_size,
                              hipStream_t stream) {
    const float* x   = (const float*)d_in[0];
    const float* adj = (const float*)d_in[1];
    const float* h0  = (const float*)d_in[2];
    const float* c0  = (const float*)d_in[3];
    const float* Wx  = (const float*)d_in[4];
    const float* Wh  = (const float*)d_in[5];
    const float* bg  = (const float*)d_in[6];
    const float* W1  = (const float*)d_in[7];
    const float* b1  = (const float*)d_in[8];
    const float* W2  = (const float*)d_in[9];
    const float* b2  = (const float*)d_in[10];
    float* out = (float*)d_out;

    const int NE = BB * NN * HH;              // 131072 floats per h buffer
    float* ws = (float*)d_ws;
    float* hA = ws;
    float* hB = ws + NE;
    unsigned* bar = (unsigned*)(ws + 2 * NE);

    bar_init<<<(BARSZ + 255) / 256, 256, 0, stream>>>(bar);

    void* args[] = { (void*)&x, (void*)&adj, (void*)&h0, (void*)&c0,
                     (void*)&Wx, (void*)&Wh, (void*)&bg,
                     (void*)&W1, (void*)&b1, (void*)&W2, (void*)&b2,
                     (void*)&out, (void*)&hA, (void*)&hB, (void*)&bar };
    hipLaunchCooperativeKernel((void*)gnn_lstm_persist,
                               dim3(NBLK), dim3(THREADS), args, 0, stream);
}

// Round 7
// 801.226 us; speedup vs baseline: 1.2402x; 1.0071x over previous
//
#include <hip/hip_runtime.h>
#include <math.h>

// Problem constants
#define BB   4
#define SS   96
#define NN   512
#define DD   8
#define HH   64
#define G4   256    // 4*H
#define OUTK 24

#define THREADS 512
#define NBLK    256   // 4 batches x 64 blocks, cooperative (co-resident, 1/CU)
#define RPB     8     // adj rows per block
#define AST     580   // a_lds row stride
#define AHWS    516   // u_lds per-wave stride
#define CSTR    64    // u32 stride per counter (256 B line)
#define BARSZ   (BB * 8 * CSTR)   // 8 wave-id counters per batch

typedef float f32x4 __attribute__((ext_vector_type(4)));

// ---------------------------------------------------------------------------
__global__ void bar_init(unsigned* __restrict__ bar) {
    const int i = blockIdx.x * 256 + threadIdx.x;
    if (i < BARSZ) bar[i] = 0u;
}

__device__ __forceinline__ float sigm_f(float v) { return 1.f / (1.f + __expf(-v)); }
__device__ __forceinline__ float tanh_f(float v) { return 1.f - 2.f / (__expf(2.f * v) + 1.f); }

__device__ __forceinline__ void vfma(f32x4& d, float s, f32x4 v) {
    d.x = fmaf(s, v.x, d.x); d.y = fmaf(s, v.y, d.y);
    d.z = fmaf(s, v.z, d.z); d.w = fmaf(s, v.w, d.w);
}

// ---------------------------------------------------------------------------
__global__ __launch_bounds__(THREADS, 2) void gnn_lstm_persist(
    const float* __restrict__ x,    // [B][S][N][D]
    const float* __restrict__ adj,  // [B][S][N][N]
    const float* __restrict__ h0,   // [B][N][H]
    const float* __restrict__ c0,   // [B][N][H]
    const float* __restrict__ Wx,   // [D][256]
    const float* __restrict__ Wh,   // [H][256]
    const float* __restrict__ bg,   // [256]
    const float* __restrict__ W1, const float* __restrict__ b1,
    const float* __restrict__ W2, const float* __restrict__ b2,
    float* __restrict__ out,        // [4][24]
    float* __restrict__ hA, float* __restrict__ hB,
    unsigned* __restrict__ bar)
{
    __shared__ float a_lds[RPB * AST];   // adj tile (stride-swizzled)
    __shared__ float x_lds[NN * DD];     // x slice
    __shared__ float u_lds[8 * AHWS];    // union: ah wave-partials | g partials
    __shared__ float ax_part[THREADS];
    __shared__ float ah_lds[RPB * HH];
    __shared__ float ax_s[RPB * DD];
    __shared__ float hh_s[HH];
    __shared__ float z1_s[32];

    const int tid  = threadIdx.x;
    const int bid  = blockIdx.x;
    const int b    = bid >> 6;           // batch
    const int slot = bid & 63;           // 0..63 within batch
    const int n0   = slot * RPB;
    const int r_g  = tid >> 6;           // wave id = owned row
    const int j_g  = tid & 63;

    // per-(batch, wave-id) arrival counters; each on its own 256B line.
    // counter[b][w] reaches 64*(t+1) == all 64 blocks' wave w drained h(t+1).
    unsigned* const cbase = bar + b * 8 * CSTR;
    unsigned* const cmine = cbase + r_g * CSTR;          // arrival target
    unsigned* const cpoll = cbase + (tid & 7) * CSTR;    // poll: lane l watches l&7

    // ---- persistent per-thread state -------------------------------------
    const int half = tid >> 8;           // 0/1
    const int jj   = tid & 255;          // gate column
    float whcol[36];
    if (half == 0) {
        #pragma unroll
        for (int k = 0; k < 36; ++k) whcol[k] = Wh[k * G4 + jj];
    } else {
        #pragma unroll
        for (int k = 0; k < 28; ++k) whcol[k] = Wh[(36 + k) * G4 + jj];
        #pragma unroll
        for (int d = 0; d < 8; ++d)  whcol[28 + d] = Wx[d * G4 + jj];
    }
    const float bias = (half == 0) ? bg[jj] : 0.f;
    const size_t sidx = ((size_t)b * NN + n0 + r_g) * HH + j_g;
    float c_reg = c0[sidx];

    // ---- stage adj(0), x(0) ----------------------------------------------
    {
        const float* ab = adj + (((size_t)b * SS + 0) * NN + n0) * NN;
        const float* xb = x + ((size_t)b * SS + 0) * (NN * DD);
        f32x4 pa0 = *(const f32x4*)(ab + tid * 4);
        f32x4 pa1 = *(const f32x4*)(ab + 2048 + tid * 4);
        f32x4 px0 = *(const f32x4*)(xb + tid * 4);
        f32x4 px1 = *(const f32x4*)(xb + 2048 + tid * 4);
        const int f0 = tid * 4;
        *(f32x4*)(a_lds + (f0 >> 9) * AST + (f0 & 511)) = pa0;
        const int f1 = 2048 + tid * 4;
        *(f32x4*)(a_lds + (f1 >> 9) * AST + (f1 & 511)) = pa1;
        *(f32x4*)(x_lds + tid * 4) = px0;
        *(f32x4*)(x_lds + 2048 + tid * 4) = px1;
    }
    __syncthreads();

    // ---- reg prefetch t=1 ----
    f32x4 qa0, qa1, qx0, qx1;
    {
        const float* ab = adj + (((size_t)b * SS + 1) * NN + n0) * NN;
        const float* xb = x + ((size_t)b * SS + 1) * (NN * DD);
        qa0 = *(const f32x4*)(ab + tid * 4);
        qa1 = *(const f32x4*)(ab + 2048 + tid * 4);
        qx0 = *(const f32x4*)(xb + tid * 4);
        qx1 = *(const f32x4*)(xb + 2048 + tid * 4);
    }

    // ---- x-agg partials for t=0 ----
    {
        const int d = tid & 7, rr = (tid >> 3) & 7, mg2 = tid >> 6;
        const float* ar = a_lds + rr * AST + mg2 * 64;
        const float* xr = x_lds + mg2 * 512 + d;
        float s = 0.f;
        #pragma unroll
        for (int mi = 0; mi < 64; ++mi) s = fmaf(ar[mi], xr[mi * 8], s);
        ax_part[tid] = s;
    }

    const float* hp = h0;
    float* hd = hB;

    const int c4 = (tid & 15) * 4;
    const int m0 = (tid >> 4) * 16;

    // ---- main recurrence -------------------------------------------------
    for (int t = 0; t < SS; ++t) {
        // phase A: 16 h-row loads (IC-coherent), pipelined with FMA chunks
        f32x4 hv[16];
        {
            const float* hpb = hp + (size_t)b * NN * HH;
            const unsigned long long hbase =
                (unsigned long long)(const void*)(hpb + (size_t)m0 * HH + c4);
#define HLOAD(I, OFFS) \
            asm volatile("global_load_dwordx4 %0, %1, off offset:" OFFS " sc0 sc1" \
                         : "=v"(hv[I]) : "v"(hbase) : "memory")
            HLOAD(0, "0");     HLOAD(1, "256");   HLOAD(2, "512");   HLOAD(3, "768");
            HLOAD(4, "1024");  HLOAD(5, "1280");  HLOAD(6, "1536");  HLOAD(7, "1792");
            HLOAD(8, "2048");  HLOAD(9, "2304");  HLOAD(10, "2560"); HLOAD(11, "2816");
            HLOAD(12, "3072"); HLOAD(13, "3328"); HLOAD(14, "3584"); HLOAD(15, "3840");
#undef HLOAD
        }
        // per-thread 8-row x 4-col tile, pipelined against the load burst
        {
            f32x4 acc[8];
            #pragma unroll
            for (int r = 0; r < 8; ++r) acc[r] = f32x4{0.f, 0.f, 0.f, 0.f};
#define AH_CHUNK(MI4) \
            { \
                _Pragma("unroll") \
                for (int r = 0; r < 8; ++r) { \
                    const f32x4 a4 = *(const f32x4*)(a_lds + r * AST + m0 + (MI4)); \
                    vfma(acc[r], a4.x, hv[(MI4) + 0]); \
                    vfma(acc[r], a4.y, hv[(MI4) + 1]); \
                    vfma(acc[r], a4.z, hv[(MI4) + 2]); \
                    vfma(acc[r], a4.w, hv[(MI4) + 3]); \
                } \
            }
            // NOTE: up to 4 older prefetch loads may still be outstanding;
            // vmcnt(12) therefore also covers them before hv[0..3] (oldest-first).
            asm volatile("s_waitcnt vmcnt(12)" ::: "memory");
            __builtin_amdgcn_sched_barrier(0);
            AH_CHUNK(0)
            asm volatile("s_waitcnt vmcnt(8)" ::: "memory");
            __builtin_amdgcn_sched_barrier(0);
            AH_CHUNK(4)
            asm volatile("s_waitcnt vmcnt(4)" ::: "memory");
            __builtin_amdgcn_sched_barrier(0);
            AH_CHUNK(8)
            asm volatile("s_waitcnt vmcnt(0)" ::: "memory");
            __builtin_amdgcn_sched_barrier(0);
            AH_CHUNK(12)
#undef AH_CHUNK
            #pragma unroll
            for (int r = 0; r < 8; ++r) {
                acc[r].x += __shfl_xor(acc[r].x, 16); acc[r].y += __shfl_xor(acc[r].y, 16);
                acc[r].z += __shfl_xor(acc[r].z, 16); acc[r].w += __shfl_xor(acc[r].w, 16);
                acc[r].x += __shfl_xor(acc[r].x, 32); acc[r].y += __shfl_xor(acc[r].y, 32);
                acc[r].z += __shfl_xor(acc[r].z, 32); acc[r].w += __shfl_xor(acc[r].w, 32);
            }
            if ((tid & 48) == 0) {
                const int w = tid >> 6;
                #pragma unroll
                for (int r = 0; r < 8; ++r)
                    *(f32x4*)(u_lds + w * AHWS + r * 64 + c4) = acc[r];
            }
        }
        __syncthreads();   // barrier A

        // reduce wave partials -> ah_lds / ax_s
        {
            float s = 0.f;
            #pragma unroll
            for (int w2 = 0; w2 < 8; ++w2) s += u_lds[w2 * AHWS + tid];
            ah_lds[tid] = s;
            if (tid < 64) {
                float s2 = 0.f;
                #pragma unroll
                for (int w2 = 0; w2 < 8; ++w2) s2 += ax_part[w2 * 64 + tid];
                ax_s[tid] = s2;
            }
        }
        __syncthreads();   // barrier B

        // phase B: g[r][jj] = ah@Wh + ax@Wx + b (36 / 28+8 split over halves)
        {
            float g[8];
            #pragma unroll
            for (int r = 0; r < 8; ++r) g[r] = bias;
            if (half == 0) {
                #pragma unroll
                for (int k4 = 0; k4 < 36; k4 += 4) {
                    #pragma unroll
                    for (int r = 0; r < 8; ++r) {
                        const f32x4 a4 = *(const f32x4*)(ah_lds + r * 64 + k4);
                        g[r] = fmaf(a4.x, whcol[k4 + 0], g[r]);
                        g[r] = fmaf(a4.y, whcol[k4 + 1], g[r]);
                        g[r] = fmaf(a4.z, whcol[k4 + 2], g[r]);
                        g[r] = fmaf(a4.w, whcol[k4 + 3], g[r]);
                    }
                }
            } else {
                #pragma unroll
                for (int k4 = 0; k4 < 28; k4 += 4) {
                    #pragma unroll
                    for (int r = 0; r < 8; ++r) {
                        const f32x4 a4 = *(const f32x4*)(ah_lds + r * 64 + 36 + k4);
                        g[r] = fmaf(a4.x, whcol[k4 + 0], g[r]);
                        g[r] = fmaf(a4.y, whcol[k4 + 1], g[r]);
                        g[r] = fmaf(a4.z, whcol[k4 + 2], g[r]);
                        g[r] = fmaf(a4.w, whcol[k4 + 3], g[r]);
                    }
                }
                #pragma unroll
                for (int d4 = 0; d4 < 8; d4 += 4) {
                    #pragma unroll
                    for (int r = 0; r < 8; ++r) {
                        const f32x4 a4 = *(const f32x4*)(ax_s + r * 8 + d4);
                        g[r] = fmaf(a4.x, whcol[28 + d4 + 0], g[r]);
                        g[r] = fmaf(a4.y, whcol[28 + d4 + 1], g[r]);
                        g[r] = fmaf(a4.z, whcol[28 + d4 + 2], g[r]);
                        g[r] = fmaf(a4.w, whcol[28 + d4 + 3], g[r]);
                    }
                }
            }
            #pragma unroll
            for (int r = 0; r < 8; ++r) u_lds[(half * 8 + r) * 256 + jj] = g[r];
        }
        __syncthreads();   // barrier C

        // gates + state update
        float hn;
        {
            const float gi = u_lds[r_g * 256 + j_g]       + u_lds[(8 + r_g) * 256 + j_g];
            const float gf = u_lds[r_g * 256 + 64 + j_g]  + u_lds[(8 + r_g) * 256 + 64 + j_g];
            const float go = u_lds[r_g * 256 + 128 + j_g] + u_lds[(8 + r_g) * 256 + 128 + j_g];
            const float gg = u_lds[r_g * 256 + 192 + j_g] + u_lds[(8 + r_g) * 256 + 192 + j_g];
            const float ig = sigm_f(gi);
            const float fg = sigm_f(gf);
            const float og = sigm_f(go);
            const float gt = tanh_f(gg);
            c_reg = fg * c_reg + ig * gt;
            hn = og * tanh_f(c_reg);
        }
        if (t == SS - 1) {
            if (slot == 0 && tid < 64) hh_s[tid] = hn;   // wave 0 owns node 0
            break;
        }
        // write-through h store, per-WAVE drain, per-wave arrival (EARLY:
        // before staging/barrier — arrival no longer waits on block-wide work)
        {
            const unsigned long long haddr = (unsigned long long)(const void*)(hd + sidx);
            asm volatile("global_store_dword %0, %1, off sc0 sc1"
                         :: "v"(haddr), "v"(hn) : "memory");
            asm volatile("s_waitcnt vmcnt(0)" ::: "memory");   // this wave's row in IC
        }
        if ((tid & 63) == 0)
            __hip_atomic_fetch_add(cmine, 1u, __ATOMIC_RELAXED, __HIP_MEMORY_SCOPE_AGENT);

        // stage t+1 LDS from regs (disjoint from u_lds still read by slow waves)
        {
            const int f0 = tid * 4;
            *(f32x4*)(a_lds + (f0 >> 9) * AST + (f0 & 511)) = qa0;
            const int f1 = 2048 + tid * 4;
            *(f32x4*)(a_lds + (f1 >> 9) * AST + (f1 & 511)) = qa1;
            *(f32x4*)(x_lds + tid * 4) = qx0;
            *(f32x4*)(x_lds + 2048 + tid * 4) = qx1;
        }
        __syncthreads();   // staging visible; all gate u_lds reads done

        // reg prefetch t+2 (lands during next step)
        {
            const int t2 = (t + 2 < SS) ? t + 2 : SS - 1;
            const float* ab = adj + (((size_t)b * SS + t2) * NN + n0) * NN;
            const float* xb = x + ((size_t)b * SS + t2) * (NN * DD);
            qa0 = *(const f32x4*)(ab + tid * 4);
            qa1 = *(const f32x4*)(ab + 2048 + tid * 4);
            qx0 = *(const f32x4*)(xb + tid * 4);
            qx1 = *(const f32x4*)(xb + 2048 + tid * 4);
        }

        // x-agg partials for t+1 (overlaps the arrival-propagation window)
        {
            const int d = tid & 7, rr = (tid >> 3) & 7, mg2 = tid >> 6;
            const float* ar = a_lds + rr * AST + mg2 * 64;
            const float* xr = x_lds + mg2 * 512 + d;
            float s = 0.f;
            #pragma unroll
            for (int mi = 0; mi < 64; ++mi) s = fmaf(ar[mi], xr[mi * 8], s);
            ax_part[tid] = s;
        }

        // per-wave poll: lane l watches counter[l&7]; all 8 counters at
        // 64*(t+1) == every block's every wave drained its h(t+1) row.
        // No trailing syncthreads: each wave slips into phase A on its own
        // (u_lds write hazard cleared by the post-staging barrier above).
        {
            const unsigned tgt = 64u * (unsigned)(t + 1);
            for (;;) {
                const unsigned v = __hip_atomic_load(cpoll, __ATOMIC_RELAXED,
                                                     __HIP_MEMORY_SCOPE_AGENT);
                if (__all(v >= tgt)) break;
                __builtin_amdgcn_s_sleep(1);
            }
        }
        __builtin_amdgcn_sched_barrier(0);

        hp = hd;
        hd = (hd == hA) ? hB : hA;
    }

    // ---- per-batch readout head (block owning node 0 of each batch) ------
    if (slot == 0) {
        __syncthreads();
        if (tid < 32) {
            float s = b1[tid];
            #pragma unroll
            for (int j = 0; j < 64; ++j) s = fmaf(hh_s[j], W1[j * 32 + tid], s);
            z1_s[tid] = fmaxf(s, 0.f);
        }
        __syncthreads();
        if (tid < OUTK) {
            float s = b2[tid];
            #pragma unroll
            for (int k = 0; k < 32; ++k) s = fmaf(z1_s[k], W2[k * 24 + tid], s);
            out[b * OUTK + tid] = s;
        }
    }
}

// ---------------------------------------------------------------------------
extern "C" void kernel_launch(void* const* d_in, const int* in_sizes, int n_in,
                              void* d_out, int out_size, void* d_ws, size_t ws_size,
                              hipStream_t stream) {
    const float* x   = (const float*)d_in[0];
    const float* adj = (const float*)d_in[1];
    const float* h0  = (const float*)d_in[2];
    const float* c0  = (const float*)d_in[3];
    const float* Wx  = (const float*)d_in[4];
    const float* Wh  = (const float*)d_in[5];
    const float* bg  = (const float*)d_in[6];
    const float* W1  = (const float*)d_in[7];
    const float* b1  = (const float*)d_in[8];
    const float* W2  = (const float*)d_in[9];
    const float* b2  = (const float*)d_in[10];
    float* out = (float*)d_out;

    const int NE = BB * NN * HH;              // 131072 floats per h buffer
    float* ws = (float*)d_ws;
    float* hA = ws;
    float* hB = ws + NE;
    unsigned* bar = (unsigned*)(ws + 2 * NE);

    bar_init<<<(BARSZ + 255) / 256, 256, 0, stream>>>(bar);

    void* args[] = { (void*)&x, (void*)&adj, (void*)&h0, (void*)&c0,
                     (void*)&Wx, (void*)&Wh, (void*)&bg,
                     (void*)&W1, (void*)&b1, (void*)&W2, (void*)&b2,
                     (void*)&out, (void*)&hA, (void*)&hB, (void*)&bar };
    hipLaunchCooperativeKernel((void*)gnn_lstm_persist,
                               dim3(NBLK), dim3(THREADS), args, 0, stream);
}